// Round 2
// baseline (19.831 us; speedup 1.0000x reference)
//
#include <hip/hip_runtime.h>

// Paste2dMulti: N=64, M=8, C=3, H=W=64, canvas l=256.
// Gather form: out[n,r,col] = min(1, sum_m mask_y(r)*mask_x(col) * sum_c img[n,m,c,r-y0,col-x0])
// One wave = one output row (64 lanes x 4 cols). One block = 4 rows.

__device__ __forceinline__ float clamp01(float v) {
    return fminf(fmaxf(v, 0.0f), 1.0f);   // -> v_med3_f32
}

__global__ __launch_bounds__(256) void Paste2dMulti_kernel(
    const float* __restrict__ coords,   // [64][8][4]
    const float* __restrict__ images,   // [64][8][3][64][64]
    float* __restrict__ out)            // [64][1][256][256]
{
    const int bid  = blockIdx.x;          // 64 n * 64 row-groups
    const int n    = bid >> 6;            // block-uniform
    const int rg   = bid & 63;
    const int tid  = threadIdx.x;
    const int r    = rg * 4 + (tid >> 6); // wave-uniform row
    const int t    = tid & 63;
    const int col0 = t * 4;               // this thread's 4 output columns

    const float fr  = (float)r;
    const float fc0 = (float)col0;

    const float* cb = coords + n * 32;
    const float* ib = images + (size_t)n * (8 * 3 * 4096);

    float a0 = 0.f, a1 = 0.f, a2 = 0.f, a3 = 0.f;

    #pragma unroll
    for (int m = 0; m < 8; ++m) {
        const float c1 = cb[m * 4 + 1];
        const int   y0 = (int)c1;          // trunc (coords >= 0)
        const int   sr = r - y0;
        if (sr < 0 || sr >= 64) continue;  // wave-uniform skip (~6 of 8 m)

        const float c0 = cb[m * 4 + 0];
        const float c2 = cb[m * 4 + 2];
        const float c3 = cb[m * 4 + 3];
        const int   x0 = (int)c0;
        const int   sb = col0 - x0;        // source col of element 0
        if (sb + 3 < 0 || sb >= 64) continue;  // lane-divergent (~17/64 active)

        const float ym = clamp01(fr - c1 + 1.f) * clamp01(c3 + 1.f - fr);

        const float* p = ib + m * (3 * 4096) + sr * 64 + sb;

        float e0 = 0.f, e1 = 0.f, e2 = 0.f, e3 = 0.f;
        if (sb >= 0 && sb + 3 < 64) {
            // interior lanes: 3x dwordx4 (4B-aligned), one per channel
            const float4 u = *(const float4*)(p);
            const float4 v = *(const float4*)(p + 4096);
            const float4 w = *(const float4*)(p + 8192);
            e0 = u.x + v.x + w.x;
            e1 = u.y + v.y + w.y;
            e2 = u.z + v.z + w.z;
            e3 = u.w + v.w + w.w;
        } else {
            // <=2 boundary lanes per wave: predicated scalar loads
            if (sb + 0 >= 0 && sb + 0 < 64) e0 = p[0] + p[4096] + p[8192];
            if (sb + 1 >= 0 && sb + 1 < 64) e1 = p[1] + p[4097] + p[8193];
            if (sb + 2 >= 0 && sb + 2 < 64) e2 = p[2] + p[4098] + p[8194];
            if (sb + 3 >= 0 && sb + 3 < 64) e3 = p[3] + p[4099] + p[8195];
        }

        const float xl = 1.f - c0;   // xm_i = clamp01(fc_i + xl) * clamp01(xr - fc_i)
        const float xr = 1.f + c2;
        a0 = fmaf(clamp01(fc0 + 0.f + xl) * clamp01(xr - (fc0 + 0.f)) * ym, e0, a0);
        a1 = fmaf(clamp01(fc0 + 1.f + xl) * clamp01(xr - (fc0 + 1.f)) * ym, e1, a1);
        a2 = fmaf(clamp01(fc0 + 2.f + xl) * clamp01(xr - (fc0 + 2.f)) * ym, e2, a2);
        a3 = fmaf(clamp01(fc0 + 3.f + xl) * clamp01(xr - (fc0 + 3.f)) * ym, e3, a3);
    }

    float4 o;
    o.x = fminf(1.f, a0);
    o.y = fminf(1.f, a1);
    o.z = fminf(1.f, a2);
    o.w = fminf(1.f, a3);
    *(float4*)(out + (size_t)n * 65536 + (size_t)r * 256 + col0) = o;  // 16B aligned
}

extern "C" void kernel_launch(void* const* d_in, const int* in_sizes, int n_in,
                              void* d_out, int out_size, void* d_ws, size_t ws_size,
                              hipStream_t stream) {
    const float* coords = (const float*)d_in[0];
    const float* images = (const float*)d_in[1];
    float* out = (float*)d_out;

    // 64 batches * 64 row-groups; 256 threads = 4 rows x 64 col-groups.
    Paste2dMulti_kernel<<<64 * 64, 256, 0, stream>>>(coords, images, out);
}

// Round 3
// 16.485 us; speedup vs baseline: 1.2030x; 1.2030x over previous
//
#include <hip/hip_runtime.h>

// Paste2dMulti: N=64, M=8, C=3, H=W=64, canvas l=256.
// Gather form. Thread = one output column x 4-row vertical strip.
// All image loads are scalar dwords, coalesced across lanes (consecutive cols).
// Vertical strip amortizes coord loads / mask math / branches 4x with zero
// alignment issues (x-vectorization is impossible: sc = col - x0 arbitrary).

__device__ __forceinline__ float clamp01(float v) {
    return fminf(fmaxf(v, 0.0f), 1.0f);   // -> v_med3_f32
}

__global__ __launch_bounds__(256) void Paste2dMulti_kernel(
    const float* __restrict__ coords,   // [64][8][4]
    const float* __restrict__ images,   // [64][8][3][64][64]
    float* __restrict__ out)            // [64][1][256][256]
{
    const int bid  = blockIdx.x;       // 64 n * 64 bands
    const int n    = bid >> 6;         // block-uniform
    const int band = bid & 63;
    const int col  = threadIdx.x;      // 0..255; wave covers 64 consecutive cols
    const int r0   = band * 4;         // rows r0 .. r0+3

    const float fc = (float)col;
    const float* cb = coords + n * 32;
    const float* ib = images + (size_t)n * (8 * 3 * 4096);

    float acc[4] = {0.f, 0.f, 0.f, 0.f};

    #pragma unroll
    for (int m = 0; m < 8; ++m) {
        const float c1  = cb[m * 4 + 1];
        const int   y0  = (int)c1;         // trunc (coords >= 0)
        const int   srl = r0 - y0;         // source row of band row 0
        if (srl + 3 < 0 || srl >= 64) continue;   // wave-uniform skip

        const float c0 = cb[m * 4 + 0];
        const int   x0 = (int)c0;
        const int   sc = col - x0;
        if (sc < 0 || sc >= 64) continue;  // per-lane; execz skips ~half the waves

        const float c2 = cb[m * 4 + 2];
        const float c3 = cb[m * 4 + 3];
        const float xm = clamp01(fc - c0 + 1.f) * clamp01(c2 + 1.f - fc);

        const float* p = ib + m * (3 * 4096) + srl * 64 + sc;

        #pragma unroll
        for (int k = 0; k < 4; ++k) {
            const int sr = srl + k;            // wave-uniform validity
            if (sr < 0 || sr >= 64) continue;
            const float fr = (float)(r0 + k);
            const float ym = clamp01(fr - c1 + 1.f) * clamp01(c3 + 1.f - fr);
            const float* q = p + k * 64;
            const float s = q[0] + q[4096] + q[2 * 4096];   // 3 coalesced dwords
            acc[k] = fmaf(xm * ym, s, acc[k]);
        }
    }

    float* o = out + (size_t)n * 65536 + (size_t)r0 * 256 + col;
    o[0]       = fminf(1.f, acc[0]);
    o[256]     = fminf(1.f, acc[1]);
    o[512]     = fminf(1.f, acc[2]);
    o[768]     = fminf(1.f, acc[3]);
}

extern "C" void kernel_launch(void* const* d_in, const int* in_sizes, int n_in,
                              void* d_out, int out_size, void* d_ws, size_t ws_size,
                              hipStream_t stream) {
    const float* coords = (const float*)d_in[0];
    const float* images = (const float*)d_in[1];
    float* out = (float*)d_out;

    // 64 batches * 64 bands of 4 rows; 256 threads = one column each.
    Paste2dMulti_kernel<<<64 * 64, 256, 0, stream>>>(coords, images, out);
}